// Round 8
// baseline (27.160 us; speedup 1.0000x reference)
//
#include <hip/hip_runtime.h>

// TemporalCoding: out[b][t][f] = (spike_time(x[b][f]) == t && x[b][f] > 0) ? 1 : 0
// B=32, T=32, F=32768. Output 128 MiB f32 -> pure write-BW bound.
//
// R7: test the last untested write-pattern axis: per-wave contiguous run
// length. R0=1KiB runs (25.9us), R2/R6=4KiB runs (24.8us). Here: 16 KiB per
// wave (ILP=16, wave-chunked), block owns 64 KiB linear (half a t-plane),
// globally linear write stream, grid=2048x256. Reads re-fetch x per plane
// (L2-served, proven free by R6==R2). Every store: 64 lanes x 16B = 1 KiB
// contiguous.

constexpr int T   = 32;
constexpr int B   = 32;
constexpr int F   = 32768;
constexpr int NF4 = F / 4;        // 8192 float4 per (b,t) plane
constexpr int ILP = 16;           // float4 per thread, wave-chunked (16 KiB/wave run)

typedef float f32x4 __attribute__((ext_vector_type(4)));

__global__ __launch_bounds__(256)
void temporal_coding_kernel(const f32x4* __restrict__ x4, f32x4* __restrict__ out4) {
    const unsigned bid = blockIdx.x;   // b*64 + t*2 + h  (h = which half-plane)
    const unsigned tid = threadIdx.x;

    const int t = (bid >> 1) & (T - 1);
    // x row for batch b, plus half-plane offset (4096 f4 per half)
    const f32x4* xhalf = x4 + ((size_t)(bid >> 6) << 13) + ((size_t)(bid & 1) << 12);
    // wave-chunked within the 4096-f4 half: thread's k-th f4 at wave*1024 + k*64 + lane
    const unsigned sub = ((tid >> 6) << 10) | (tid & 63);
    f32x4* op = out4 + (((size_t)bid) << 12) + sub;   // globally linear stream

#pragma unroll
    for (int k = 0; k < ILP; ++k) {
        const f32x4 xv = xhalf[sub + k * 64];
        f32x4 r;
#pragma unroll
        for (int j = 0; j < 4; ++j) {
            float xn = xv[j];
            xn = xn < 0.0f ? 0.0f : (xn > 1.0f ? 1.0f : xn);
            int s = (int)((1.0f - xn) * 31.0f);   // trunc == astype(int32) for s>=0
            s = s < 0 ? 0 : (s > 31 ? 31 : s);
            r[j] = (xn > 0.0f && s == t) ? 1.0f : 0.0f;
        }
        op[k * 64] = r;
    }
}

extern "C" void kernel_launch(void* const* d_in, const int* in_sizes, int n_in,
                              void* d_out, int out_size, void* d_ws, size_t ws_size,
                              hipStream_t stream) {
    const f32x4* x4 = (const f32x4*)d_in[0];
    f32x4* out4 = (f32x4*)d_out;

    const int grid = B * T * NF4 / (256 * ILP);   // 2048 blocks, 256 threads, 16 f4/thread
    temporal_coding_kernel<<<grid, 256, 0, stream>>>(x4, out4);
}

// Round 9
// 24.748 us; speedup vs baseline: 1.0975x; 1.0975x over previous
//
#include <hip/hip_runtime.h>

// TemporalCoding: out[b][t][f] = (spike_time(x[b][f]) == t && x[b][f] > 0) ? 1 : 0
// B=32, T=32, F=32768. Output 128 MiB f32 -> pure write-BW bound.
//
// FINAL (= R2, best measured: 24.83 us ~ 5.6 TB/s effective).
// Linear fill-clone write stream with WAVE-chunked ILP 4:
// - Each block owns 1024 consecutive float4s (16 KiB) of output, entirely
//   within one t-plane; global thread order == output address order, so the
//   write stream is perfectly linear (same shape as fillBufferAligned).
// - Thread's k-th element at wave*256 + k*64 + lane: every store instruction
//   is 64 lanes x 16 B = 1 KiB contiguous; 4 KiB contiguous per wave -- the
//   measured sweet spot (1 KiB: 25.9, 4 KiB: 24.8, 8 KiB: 25.3, 16 KiB: 27.2).
// - x (4 MiB) is logically re-read once per t-plane but is L2/L3-resident
//   (proven free: register-resident variant R6 ties at 24.86 us).
// - Plain stores; nontemporal hint measured -15% (R4).
// Axes probed and rejected: nt stores, ILP {8,16}, register-resident full-t,
// per-thread-consecutive layout (R1, -2x). Three distinct structures converge
// at ~24.8 us => write-path roofline for a 128 MiB dispatch (138 MB @ 6.7 TB/s
// = 20.7 us + ~2-3 us launch/ramp).

constexpr int T   = 32;
constexpr int B   = 32;
constexpr int F   = 32768;
constexpr int NF4 = F / 4;       // 8192 float4 per (b,t) plane

__global__ __launch_bounds__(256)
void temporal_coding_kernel(const float4* __restrict__ x4, float4* __restrict__ out4) {
    const unsigned bid = blockIdx.x;          // enumerates (b, t, chunk): b*256 + t*8 + c
    const unsigned tid = threadIdx.x;

    const int      t    = (bid >> 3) & (T - 1);
    const float4*  xrow = x4 + ((size_t)(bid >> 8) << 13);        // + b*NF4
    const unsigned sub  = ((tid >> 6) << 8) | (tid & 63);         // wave*256 + lane
    const unsigned f4_0 = ((bid & 7) << 10) + sub;                // f4 index, k=0
    float4*        op   = out4 + (((size_t)bid) << 10) + sub;     // linear: bid*1024

#pragma unroll
    for (int k = 0; k < 4; ++k) {
        const float4 xv = xrow[f4_0 + k * 64];
        float v[4] = {xv.x, xv.y, xv.z, xv.w};
        float r[4];
#pragma unroll
        for (int j = 0; j < 4; ++j) {
            float xn = v[j];
            xn = xn < 0.0f ? 0.0f : (xn > 1.0f ? 1.0f : xn);
            int s = (int)((1.0f - xn) * 31.0f);   // trunc == astype(int32) for s>=0
            s = s < 0 ? 0 : (s > 31 ? 31 : s);
            r[j] = (xn > 0.0f && s == t) ? 1.0f : 0.0f;
        }
        op[k * 64] = make_float4(r[0], r[1], r[2], r[3]);
    }
}

extern "C" void kernel_launch(void* const* d_in, const int* in_sizes, int n_in,
                              void* d_out, int out_size, void* d_ws, size_t ws_size,
                              hipStream_t stream) {
    const float4* x4 = (const float4*)d_in[0];
    float4* out4 = (float4*)d_out;

    const int grid = B * T * (NF4 / 1024);   // 8192 blocks x 256 threads, 4 float4/thread
    temporal_coding_kernel<<<grid, 256, 0, stream>>>(x4, out4);
}